// Round 1
// baseline (424.368 us; speedup 1.0000x reference)
//
#include <hip/hip_runtime.h>
#include <float.h>
#include <math.h>

typedef __bf16 bf16;
typedef __attribute__((ext_vector_type(8))) __bf16 bf16x8;
typedef __attribute__((ext_vector_type(4))) __bf16 bf16x4;
typedef __attribute__((ext_vector_type(4))) float f32x4;

#define MK 544  // Mg row stride in bf16 elements; cols [0,515) real, rest zero

__device__ __forceinline__ f32x4 mfma16(bf16x8 a, bf16x8 b, f32x4 c) {
  return __builtin_amdgcn_mfma_f32_16x16x32_bf16(a, b, c, 0, 0, 0);
}

// ---------------------------------------------------------------------------
// Precompute: keys[16,64] = key_in @ k_w^T + k_b  (key_in = [led_feats, led_pos])
// M[n][k]   = sum_d q_w[d][k] * keys[n][d]   (k < 515; query_in k-order:
//             k in [0,512) -> x[w=k], k in [512,515) -> anchor)
// c[n]      = sum_d q_b[d] * keys[n][d]
// ---------------------------------------------------------------------------
__global__ __launch_bounds__(256) void acek_precompute(
    const float* __restrict__ led_feats, const float* __restrict__ led_pos,
    const float* __restrict__ q_w, const float* __restrict__ q_b,
    const float* __restrict__ k_w, const float* __restrict__ k_b,
    bf16* __restrict__ Mg, float* __restrict__ cvec) {
  __shared__ float keys[16 * 64];
  const int t = threadIdx.x;
  for (int idx = t; idx < 16 * 64; idx += 256) {
    int n = idx >> 6, d = idx & 63;
    float acc = k_b[d];
#pragma unroll
    for (int j = 0; j < 8; ++j) acc += k_w[d * 11 + j] * led_feats[n * 8 + j];
#pragma unroll
    for (int j = 0; j < 3; ++j) acc += k_w[d * 11 + 8 + j] * led_pos[n * 3 + j];
    keys[idx] = acc;
  }
  __syncthreads();
  int e = blockIdx.x * 256 + t;
  if (e < 16 * MK) {
    int n = e / MK, k = e - n * MK;
    float v = 0.f;
    if (k < 515) {
#pragma unroll 4
      for (int d = 0; d < 64; ++d) v += q_w[d * 515 + k] * keys[n * 64 + d];
    }
    Mg[e] = (bf16)v;
  }
  if (blockIdx.x == 0 && t < 16) {
    float acc = 0.f;
    for (int d = 0; d < 64; ++d) acc += q_b[d] * keys[t * 64 + d];
    cvec[t] = acc;
  }
}

// ---------------------------------------------------------------------------
// Main fused kernel: one block per batch element.
// ---------------------------------------------------------------------------
__global__ __launch_bounds__(256) void acek_main(
    const float* __restrict__ rss, const float* __restrict__ anchor,
    const float* __restrict__ ledf, const float* __restrict__ ledp,
    const int* __restrict__ fmask,
    const float* __restrict__ c1w, const float* __restrict__ c1b,
    const float* __restrict__ c2w, const float* __restrict__ c2b,
    const float* __restrict__ rw, const float* __restrict__ rb,
    const float* __restrict__ fw, const float* __restrict__ fb,
    const bf16* __restrict__ Mg, const float* __restrict__ cvec,
    float* __restrict__ out) {

  // xw : x in [w+1][ic] layout (24-col rows: 16 data cols (12 real, 4 zero),
  //      8 pad cols for bank spread). rows 0..514, row = w_actual + 1.
  // xT : query_in in [r][k] layout, rows 0..15 (12 real), k cols 0..543.
  // h1E/h1O : relu(conv1) bf16 [w][oc], even/odd logical rows (row = w+1)
  //      split so conv2's stride-2 row reads hit both 16-bank halves.
  __shared__ __align__(16) bf16 xw[515 * 24];
  __shared__ __align__(16) bf16 xT[16 * 544];
  __shared__ __align__(16) bf16 h1E[257 * 32];
  __shared__ __align__(16) bf16 h1O[256 * 32];
  __shared__ __align__(16) float parts[3 * 256];  // per-wave score partials
  __shared__ __align__(16) float att[192];
  __shared__ __align__(16) float sagg[96];
  __shared__ __align__(16) float comb[128];
  __shared__ __align__(16) float tfp[256];        // per-wave t_feat partials
  __shared__ __align__(16) float bias_lds[16];

  const int tid = threadIdx.x;
  const int lane = tid & 63;
  const int wv = tid >> 6;
  const int a15 = lane & 15;
  const int g = lane >> 4;
  const int b = blockIdx.x;

  // ---- weight A-fragments + biases into registers (global, L1-hot) ----
  // conv1: K1 = dk*16 + ic, padded to 64 (2 k-steps); zero pads on A side.
  bf16x8 w1f[2][2];
#pragma unroll
  for (int ot = 0; ot < 2; ++ot)
#pragma unroll
    for (int s = 0; s < 2; ++s) {
      bf16x8 t8;
#pragma unroll
      for (int j = 0; j < 8; ++j) {
        int k1 = s * 32 + g * 8 + j;
        int dk = k1 >> 4, ic = k1 & 15;
        float v = (ic < 12 && dk < 3) ? c1w[(ot * 16 + a15) * 36 + ic * 3 + dk] : 0.f;
        t8[j] = (bf16)v;
      }
      w1f[ot][s] = t8;
    }
  // conv2: K2 = dk*32 + ic2 = 96 exactly (3 k-steps, dk == s).
  bf16x8 w2f[4][3];
#pragma unroll
  for (int o = 0; o < 4; ++o)
#pragma unroll
    for (int s = 0; s < 3; ++s) {
      bf16x8 t8;
#pragma unroll
      for (int j = 0; j < 8; ++j) {
        int ic2 = g * 8 + j;
        t8[j] = (bf16)c2w[(o * 16 + a15) * 96 + ic2 * 3 + s];
      }
      w2f[o][s] = t8;
    }
  float b1v[2][4], b2v[4][4];
#pragma unroll
  for (int ot = 0; ot < 2; ++ot)
#pragma unroll
    for (int r = 0; r < 4; ++r) b1v[ot][r] = c1b[ot * 16 + g * 4 + r];
#pragma unroll
  for (int o = 0; o < 4; ++o)
#pragma unroll
    for (int r = 0; r < 4; ++r) b2v[o][r] = c2b[o * 16 + g * 4 + r];

  // ---- P0: zero all LDS pad regions that MFMA B-frags may touch ----
  bf16x4 zb4 = {(bf16)0.f, (bf16)0.f, (bf16)0.f, (bf16)0.f};
  bf16x8 zb8 = {(bf16)0.f, (bf16)0.f, (bf16)0.f, (bf16)0.f,
                (bf16)0.f, (bf16)0.f, (bf16)0.f, (bf16)0.f};
  for (int r = tid; r < 515; r += 256) *(bf16x4*)&xw[r * 24 + 12] = zb4;  // cols 12..15
  if (tid < 12) {  // boundary rows 0, 513, 514 cols 0..15
    int rr = (tid >> 2) == 0 ? 0 : ((tid >> 2) == 1 ? 513 : 514);
    *(bf16x4*)&xw[rr * 24 + (tid & 3) * 4] = zb4;
  }
  if (tid < 48) {  // xT rows 0..11, cols 512..543
    int r = tid >> 2, sg = tid & 3;
    *(bf16x8*)&xT[r * 544 + 512 + sg * 8] = zb8;
  }
  for (int i = tid; i < 4 * 68; i += 256) {  // xT rows 12..15 full
    int r = 12 + i / 68, sg = i - (i / 68) * 68;
    *(bf16x8*)&xT[r * 544 + sg * 8] = zb8;
  }
  if (tid < 4) *(bf16x8*)&h1E[tid * 8] = zb8;  // h1 row w=-1 (zero pad)
  __syncthreads();

  // ---- P1: stage x (coalesced float4) into xw and xT; dist bias ----
  const float* xb = rss + (size_t)b * 6144;
#pragma unroll
  for (int i = 0; i < 6; ++i) {
    int f = tid + i * 256;           // 1536 float4 per batch
    f32x4 v = ((const f32x4*)xb)[f];
    int e = f * 4;
    int w = e / 12;
    int c = e - w * 12;              // in {0,4,8}
    bf16x4 bv;
    bv[0] = (bf16)v[0]; bv[1] = (bf16)v[1]; bv[2] = (bf16)v[2]; bv[3] = (bf16)v[3];
    *(bf16x4*)&xw[(w + 1) * 24 + c] = bv;
    xT[(c + 0) * 544 + w] = bv[0];
    xT[(c + 1) * 544 + w] = bv[1];
    xT[(c + 2) * 544 + w] = bv[2];
    xT[(c + 3) * 544 + w] = bv[3];
  }
  if (tid < 36) {  // anchor -> xT cols 512..514, rows 0..11
    int r = tid / 3, j = tid - r * 3;
    xT[r * 544 + 512 + j] = (bf16)anchor[(size_t)b * 3 + j];
  }
  if (tid < 16) {
    float dx = anchor[(size_t)b * 3 + 0] - ledp[tid * 3 + 0];
    float dy = anchor[(size_t)b * 3 + 1] - ledp[tid * 3 + 1];
    float dz = anchor[(size_t)b * 3 + 2] - ledp[tid * 3 + 2];
    bias_lds[tid] = -0.5f * logf(dx * dx + dy * dy + dz * dz + 1e-8f);
  }
  __syncthreads();

  // ---- P2: conv1 MFMA (writes h1) + scores MFMA (writes parts) ----
  {
    const int dk0 = g >> 1;
    const int icb = (g & 1) * 8;
    for (int wt = wv * 8; wt < wv * 8 + 8; ++wt) {
      const int wcol = wt * 16 + a15;          // output w (B n-col)
      f32x4 c0 = {0.f, 0.f, 0.f, 0.f}, c1 = {0.f, 0.f, 0.f, 0.f};
#pragma unroll
      for (int s = 0; s < 2; ++s) {
        int row = wcol + 2 * s + dk0;          // = w + dk  (xw row = w+1 shift folded)
        bf16x8 bv = *(const bf16x8*)&xw[row * 24 + icb];
        c0 = mfma16(w1f[0][s], bv, c0);
        c1 = mfma16(w1f[1][s], bv, c1);
      }
      const int hrow = wcol + 1;
      bf16* hb = (hrow & 1) ? h1O : h1E;
      const int pr = hrow >> 1;
      bf16x4 o0, o1;
#pragma unroll
      for (int r = 0; r < 4; ++r) {
        o0[r] = (bf16)fmaxf(c0[r] + b1v[0][r], 0.f);
        o1[r] = (bf16)fmaxf(c1[r] + b1v[1][r], 0.f);
      }
      *(bf16x4*)&hb[pr * 32 + g * 4] = o0;         // oc 0..15 slice
      *(bf16x4*)&hb[pr * 32 + 16 + g * 4] = o1;    // oc 16..31 slice
    }
    if (wv < 3) {  // scores: D[r][n] = sum_k query_in[r][k] * M[k][n]
      f32x4 sac = {0.f, 0.f, 0.f, 0.f};
      for (int s = wv; s < 17; s += 3) {
        bf16x8 av = *(const bf16x8*)&xT[a15 * 544 + s * 32 + g * 8];
        bf16x8 bm = *(const bf16x8*)&Mg[a15 * 544 + s * 32 + g * 8];
        sac = mfma16(av, bm, sac);
      }
#pragma unroll
      for (int r = 0; r < 4; ++r) parts[wv * 256 + (g * 4 + r) * 16 + a15] = sac[r];
    }
  }
  __syncthreads();

  // ---- P3: conv2 MFMA + fused mean (t_feat) ; softmax ----
  {
    float tacc[4][4] = {{0.f, 0.f, 0.f, 0.f}, {0.f, 0.f, 0.f, 0.f},
                        {0.f, 0.f, 0.f, 0.f}, {0.f, 0.f, 0.f, 0.f}};
    for (int pti = 0; pti < 4; ++pti) {
      const int p = (wv * 4 + pti) * 16 + a15;   // output position (B n-col)
      f32x4 cc0 = {0.f, 0.f, 0.f, 0.f}, cc1 = {0.f, 0.f, 0.f, 0.f};
      f32x4 cc2 = {0.f, 0.f, 0.f, 0.f}, cc3 = {0.f, 0.f, 0.f, 0.f};
#pragma unroll
      for (int s = 0; s < 3; ++s) {
        const bf16* hb = (s == 1) ? h1O : h1E;   // rho=2p+s: s=0->E[p], 1->O[p], 2->E[p+1]
        bf16x8 bv = *(const bf16x8*)&hb[(p + (s >> 1)) * 32 + g * 8];
        cc0 = mfma16(w2f[0][s], bv, cc0);
        cc1 = mfma16(w2f[1][s], bv, cc1);
        cc2 = mfma16(w2f[2][s], bv, cc2);
        cc3 = mfma16(w2f[3][s], bv, cc3);
      }
#pragma unroll
      for (int r = 0; r < 4; ++r) {
        tacc[0][r] += fmaxf(cc0[r] + b2v[0][r], 0.f);
        tacc[1][r] += fmaxf(cc1[r] + b2v[1][r], 0.f);
        tacc[2][r] += fmaxf(cc2[r] + b2v[2][r], 0.f);
        tacc[3][r] += fmaxf(cc3[r] + b2v[3][r], 0.f);
      }
    }
#pragma unroll
    for (int o = 0; o < 4; ++o)
#pragma unroll
      for (int r = 0; r < 4; ++r) {
        float v = tacc[o][r];
        v += __shfl_xor(v, 1, 16);
        v += __shfl_xor(v, 2, 16);
        v += __shfl_xor(v, 4, 16);
        v += __shfl_xor(v, 8, 16);
        if (a15 == 0) tfp[wv * 64 + o * 16 + g * 4 + r] = v;
      }
  }
  if (tid < 192) {  // softmax over n within each 16-lane group
    const int r = tid >> 4, n = tid & 15;
    float s = parts[r * 16 + n] + parts[256 + r * 16 + n] + parts[512 + r * 16 + n];
    s += cvec[n] + bias_lds[n];
    if (fmask[r * 16 + n] == 0) s = -FLT_MAX;
    float mx = s;
    mx = fmaxf(mx, __shfl_xor(mx, 1, 16));
    mx = fmaxf(mx, __shfl_xor(mx, 2, 16));
    mx = fmaxf(mx, __shfl_xor(mx, 4, 16));
    mx = fmaxf(mx, __shfl_xor(mx, 8, 16));
    float e = expf(s - mx);
    float sm = e;
    sm += __shfl_xor(sm, 1, 16);
    sm += __shfl_xor(sm, 2, 16);
    sm += __shfl_xor(sm, 4, 16);
    sm += __shfl_xor(sm, 8, 16);
    att[tid] = e / sm;
  }
  __syncthreads();

  // ---- P4: t_feat finalize + s_agg ----
  if (tid < 64)
    comb[tid] = (tfp[tid] + tfp[64 + tid] + tfp[128 + tid] + tfp[192 + tid]) * (1.f / 256.f);
  if (tid < 96) {
    const int r = tid >> 3, f = tid & 7;
    float acc = 0.f;
#pragma unroll
    for (int n = 0; n < 16; ++n) acc += att[r * 16 + n] * ledf[n * 8 + f];
    sagg[tid] = acc;
  }
  __syncthreads();

  // ---- P5: s_feat = relu(red_w @ sagg + red_b) ----
  if (tid < 64) {
    float acc = rb[tid];
    const f32x4* rwv = (const f32x4*)(rw + tid * 96);
    const f32x4* sv = (const f32x4*)sagg;
#pragma unroll 6
    for (int i = 0; i < 24; ++i) {
      f32x4 a = rwv[i], s = sv[i];
      acc += a[0] * s[0] + a[1] * s[1] + a[2] * s[2] + a[3] * s[3];
    }
    comb[64 + tid] = fmaxf(acc, 0.f);
  }
  __syncthreads();

  // ---- P6: out = fus_w @ comb + fus_b ----
  if (tid < 64) {
    float acc = fb[tid];
    const f32x4* fwv = (const f32x4*)(fw + tid * 128);
    const f32x4* cv = (const f32x4*)comb;
#pragma unroll 8
    for (int i = 0; i < 32; ++i) {
      f32x4 a = fwv[i], c = cv[i];
      acc += a[0] * c[0] + a[1] * c[1] + a[2] * c[2] + a[3] * c[3];
    }
    out[(size_t)b * 64 + tid] = acc;
  }
}

extern "C" void kernel_launch(void* const* d_in, const int* in_sizes, int n_in,
                              void* d_out, int out_size, void* d_ws, size_t ws_size,
                              hipStream_t stream) {
  (void)in_sizes; (void)n_in; (void)out_size; (void)ws_size;
  const float* rss   = (const float*)d_in[0];
  const float* anch  = (const float*)d_in[1];
  const float* ledf  = (const float*)d_in[2];
  const float* ledp  = (const float*)d_in[3];
  const int*   fmask = (const int*)d_in[4];
  const float* c1w = (const float*)d_in[5];
  const float* c1b = (const float*)d_in[6];
  const float* c2w = (const float*)d_in[7];
  const float* c2b = (const float*)d_in[8];
  const float* qw  = (const float*)d_in[9];
  const float* qb  = (const float*)d_in[10];
  const float* kw  = (const float*)d_in[11];
  const float* kb  = (const float*)d_in[12];
  const float* rw  = (const float*)d_in[13];
  const float* rb  = (const float*)d_in[14];
  const float* fw  = (const float*)d_in[15];
  const float* fb  = (const float*)d_in[16];
  float* outp = (float*)d_out;

  bf16* Mg = (bf16*)d_ws;
  float* cvec = (float*)((char*)d_ws + 16 * MK * sizeof(bf16));

  acek_precompute<<<(16 * MK + 255) / 256, 256, 0, stream>>>(ledf, ledp, qw, qb, kw, kb, Mg, cvec);
  acek_main<<<8192, 256, 0, stream>>>(rss, anch, ledf, ledp, fmask, c1w, c1b, c2w, c2b,
                                      rw, rb, fw, fb, Mg, cvec, outp);
}

// Round 2
// 137.854 us; speedup vs baseline: 3.0784x; 3.0784x over previous
//
#include <hip/hip_runtime.h>
#include <float.h>
#include <math.h>

typedef __bf16 bf16;
typedef __attribute__((ext_vector_type(8))) __bf16 bf16x8;
typedef __attribute__((ext_vector_type(4))) __bf16 bf16x4;
typedef __attribute__((ext_vector_type(4))) float f32x4;
typedef long long i64;

#define MK 544  // Mg row stride (bf16); cols [0,515) real, rest zero

// workspace byte offsets
#define WS_MG   0        // bf16[16*544]          = 17408 B
#define WS_CVEC 17408    // f32[16]               = 64 B
#define WS_W1F  17472    // bf16x8[2*2*64]        = 4096 B
#define WS_W2F  21568    // i64[4*3*64]           = 6144 B

__device__ __forceinline__ f32x4 mfma16(bf16x8 a, bf16x8 b, f32x4 c) {
  return __builtin_amdgcn_mfma_f32_16x16x32_bf16(a, b, c, 0, 0, 0);
}
__device__ __forceinline__ f32x4 mfma8(i64 a, i64 b, f32x4 c) {
  return __builtin_amdgcn_mfma_f32_16x16x32_fp8_fp8(a, b, c, 0, 0, 0);
}

// ---------------------------------------------------------------------------
// Precompute (grid 35): blocks 0..33 build Mg[n][k] (bf16, zero k>=515) and
// cvec[n]; block 34 builds the conv weight fragment tables (W1F bf16,
// W2F fp8 scaled x16).
// ---------------------------------------------------------------------------
__global__ __launch_bounds__(256) void acek_pre(
    const float* __restrict__ led_feats, const float* __restrict__ led_pos,
    const float* __restrict__ q_w, const float* __restrict__ q_b,
    const float* __restrict__ k_w, const float* __restrict__ k_b,
    const float* __restrict__ c1w, const float* __restrict__ c2w,
    char* __restrict__ ws) {
  bf16* Mg = (bf16*)(ws + WS_MG);
  float* cvec = (float*)(ws + WS_CVEC);
  bf16x8* W1F = (bf16x8*)(ws + WS_W1F);
  i64* W2F = (i64*)(ws + WS_W2F);
  const int t = threadIdx.x;

  if (blockIdx.x == 34) {
    // conv1 fragments: frag idx = (ot*2+s)*64+lane, elem j <-> k1=s*32+g*8+j
    {
      int ot = t >> 7, s = (t >> 6) & 1, lane = t & 63;
      int g = lane >> 4, a15 = lane & 15;
      bf16x8 f;
#pragma unroll
      for (int j = 0; j < 8; ++j) {
        int k1 = s * 32 + g * 8 + j;
        int dk = k1 >> 4, ic = k1 & 15;
        float v = (ic < 12 && dk < 3) ? c1w[(ot * 16 + a15) * 36 + ic * 3 + dk] : 0.f;
        f[j] = (bf16)v;
      }
      W1F[t] = f;
    }
    // conv2 fragments (fp8, x16): frag idx = (o*3+s)*64+lane, elem j <-> ic2=g*8+j
    for (int r = 0; r < 3; ++r) {
      int fi = t + r * 256;
      int o = fi / 192, rem = fi - o * 192;
      int s = rem >> 6, lane = rem & 63;
      int g = lane >> 4, a15 = lane & 15;
      float v[8];
#pragma unroll
      for (int j = 0; j < 8; ++j)
        v[j] = 16.f * c2w[(o * 16 + a15) * 96 + (g * 8 + j) * 3 + s];
      int lo = __builtin_amdgcn_cvt_pk_fp8_f32(v[0], v[1], 0, false);
      lo = __builtin_amdgcn_cvt_pk_fp8_f32(v[2], v[3], lo, true);
      int hi = __builtin_amdgcn_cvt_pk_fp8_f32(v[4], v[5], 0, false);
      hi = __builtin_amdgcn_cvt_pk_fp8_f32(v[6], v[7], hi, true);
      W2F[fi] = ((i64)(unsigned)lo) | (((i64)hi) << 32);
    }
    return;
  }

  __shared__ float keys[16 * 64];
  for (int idx = t; idx < 16 * 64; idx += 256) {
    int n = idx >> 6, d = idx & 63;
    float acc = k_b[d];
#pragma unroll
    for (int j = 0; j < 8; ++j) acc += k_w[d * 11 + j] * led_feats[n * 8 + j];
#pragma unroll
    for (int j = 0; j < 3; ++j) acc += k_w[d * 11 + 8 + j] * led_pos[n * 3 + j];
    keys[idx] = acc;
  }
  __syncthreads();
  int e = blockIdx.x * 256 + t;
  if (e < 16 * MK) {
    int n = e / MK, k = e - n * MK;
    float v = 0.f;
    if (k < 515) {
#pragma unroll 4
      for (int d = 0; d < 64; ++d) v += q_w[d * 515 + k] * keys[n * 64 + d];
    }
    Mg[e] = (bf16)v;
  }
  if (blockIdx.x == 0 && t < 16) {
    float acc = 0.f;
    for (int d = 0; d < 64; ++d) acc += q_b[d] * keys[t * 64 + d];
    cvec[t] = acc;
  }
}

// ---------------------------------------------------------------------------
// Main: one block per batch element; 4 waves.
//   waves 0-2: conv1 (MFMA bf16) -> h1 fp8 in LDS
//   wave 3   : scores (direct-global A-frags) + softmax + s_agg + s_feat
//   all      : conv2 (MFMA fp8) + pooled mean; wave 0: fusion epilogue
// ---------------------------------------------------------------------------
__global__ __launch_bounds__(256, 4) void acek_main(
    const float* __restrict__ rss, const float* __restrict__ anchor,
    const float* __restrict__ ledf, const float* __restrict__ ledp,
    const int* __restrict__ fmask,
    const float* __restrict__ c1b, const float* __restrict__ c2b,
    const float* __restrict__ rw, const float* __restrict__ rb,
    const float* __restrict__ fw, const float* __restrict__ fb,
    const bf16* __restrict__ Mg, const float* __restrict__ cvec,
    const bf16x8* __restrict__ W1F, const i64* __restrict__ W2F,
    float* __restrict__ out) {

  // xw : x bf16, rows 0..514 (row = x-idx+1), 16 cols (12 real), 32B rows,
  //      swizzled: byte ^= ((row&4)<<2). rows 0,513,514 zero; cols 12-15 zero.
  // h1 : relu(conv1) fp8 [row][oc], row = conv1-w + 1 (row 0 = zero pad),
  //      40B row stride (32 data + 8 pad).
  __shared__ __align__(16) bf16 xw[515 * 16];
  __shared__ __align__(16) unsigned char h1[513 * 40];
  __shared__ __align__(16) float att[192];
  __shared__ __align__(16) float sagg[96];
  __shared__ __align__(16) float comb[128];
  __shared__ __align__(16) float tfp[256];

  const int tid = threadIdx.x;
  const int lane = tid & 63;
  const int wv = tid >> 6;
  const int a15 = lane & 15;
  const int g = lane >> 4;
  const int b = blockIdx.x;
  char* xwb = (char*)xw;
  char* h1b = (char*)h1;

  // ---- phase 0: fragment/bias loads, zero pads, stage x ----
  bf16x8 w1f[2][2];
#pragma unroll
  for (int ot = 0; ot < 2; ++ot)
#pragma unroll
    for (int s = 0; s < 2; ++s) w1f[ot][s] = W1F[(ot * 2 + s) * 64 + lane];
  i64 w2f[4][3];
#pragma unroll
  for (int o = 0; o < 4; ++o)
#pragma unroll
    for (int s = 0; s < 3; ++s) w2f[o][s] = W2F[(o * 3 + s) * 64 + lane];
  f32x4 b1v[2], b2s[4];
#pragma unroll
  for (int ot = 0; ot < 2; ++ot) b1v[ot] = *(const f32x4*)&c1b[ot * 16 + g * 4];
#pragma unroll
  for (int o = 0; o < 4; ++o) {
    f32x4 tmp = *(const f32x4*)&c2b[o * 16 + g * 4];
    b2s[o] = tmp * 16.f;  // weight scale folded into bias
  }

  bf16x4 z4 = {(bf16)0.f, (bf16)0.f, (bf16)0.f, (bf16)0.f};
  for (int r = tid; r < 515; r += 256)
    *(bf16x4*)(xwb + r * 32 + (24 ^ ((r & 4) << 2))) = z4;   // cols 12-15
  if (tid < 12) {                                            // rows 0,513,514 full
    int rr = (tid >> 2) == 0 ? 0 : ((tid >> 2) == 1 ? 513 : 514);
    *(bf16x4*)(xwb + rr * 32 + (((tid & 3) * 8) ^ ((rr & 4) << 2))) = z4;
  }
  if (tid < 4) *(i64*)(h1b + tid * 8) = 0;                   // h1 row 0

  const float* xb = rss + (size_t)b * 6144;
#pragma unroll
  for (int i = 0; i < 6; ++i) {
    int f = tid + i * 256;
    f32x4 v = ((const f32x4*)xb)[f];
    int e = f * 4;
    int w = e / 12;
    int c = e - w * 12;  // {0,4,8}
    bf16x4 bv;
    bv[0] = (bf16)v[0]; bv[1] = (bf16)v[1]; bv[2] = (bf16)v[2]; bv[3] = (bf16)v[3];
    int row = w + 1;
    *(bf16x4*)(xwb + row * 32 + ((c * 2) ^ ((row & 4) << 2))) = bv;
  }
  __syncthreads();  // barrier A

  // ---- phase 1 ----
  if (wv < 3) {
    // conv1: tiles 11/11/10
    const int t0 = wv * 11;
    const int tn = (wv == 2) ? 10 : 11;
    const int dk0 = g >> 1;
    const int icb16 = (g & 1) << 4;  // byte offset of ic block
    for (int wt = t0; wt < t0 + tn; ++wt) {
      const int wcol = wt * 16 + a15;
      f32x4 c0 = {0.f, 0.f, 0.f, 0.f}, c1 = {0.f, 0.f, 0.f, 0.f};
#pragma unroll
      for (int s = 0; s < 2; ++s) {
        int row = wcol + 2 * s + dk0;
        bf16x8 bv = *(const bf16x8*)(xwb + row * 32 + (icb16 ^ ((row & 4) << 2)));
        c0 = mfma16(w1f[0][s], bv, c0);
        c1 = mfma16(w1f[1][s], bv, c1);
      }
      const int hrow = wcol + 1;
      float v0 = fmaxf(c0[0] + b1v[0][0], 0.f), v1 = fmaxf(c0[1] + b1v[0][1], 0.f);
      float v2 = fmaxf(c0[2] + b1v[0][2], 0.f), v3 = fmaxf(c0[3] + b1v[0][3], 0.f);
      int pk0 = __builtin_amdgcn_cvt_pk_fp8_f32(v0, v1, 0, false);
      pk0 = __builtin_amdgcn_cvt_pk_fp8_f32(v2, v3, pk0, true);
      *(int*)(h1b + hrow * 40 + g * 4) = pk0;
      v0 = fmaxf(c1[0] + b1v[1][0], 0.f); v1 = fmaxf(c1[1] + b1v[1][1], 0.f);
      v2 = fmaxf(c1[2] + b1v[1][2], 0.f); v3 = fmaxf(c1[3] + b1v[1][3], 0.f);
      int pk1 = __builtin_amdgcn_cvt_pk_fp8_f32(v0, v1, 0, false);
      pk1 = __builtin_amdgcn_cvt_pk_fp8_f32(v2, v3, pk1, true);
      *(int*)(h1b + hrow * 40 + 16 + g * 4) = pk1;
    }
  } else {
    // wave 3: full attention branch
    const float anc0 = anchor[(size_t)b * 3 + 0];
    const float anc1 = anchor[(size_t)b * 3 + 1];
    const float anc2 = anchor[(size_t)b * 3 + 2];
    const int rcl = (a15 < 12) ? a15 : 11;
    const bf16* MgR = Mg + a15 * MK;
    f32x4 sac = {0.f, 0.f, 0.f, 0.f};
#pragma unroll 4
    for (int s = 0; s < 16; ++s) {
      const float* xs = xb + (s * 32 + g * 8) * 12 + rcl;
      bf16x8 av;
#pragma unroll
      for (int j = 0; j < 8; ++j) av[j] = (bf16)xs[j * 12];
      bf16x8 bm = *(const bf16x8*)&MgR[s * 32 + g * 8];
      sac = mfma16(av, bm, sac);
    }
    {  // anchor k-step (k = 512..514)
      bf16x8 av = {(bf16)0.f, (bf16)0.f, (bf16)0.f, (bf16)0.f,
                   (bf16)0.f, (bf16)0.f, (bf16)0.f, (bf16)0.f};
      if (g == 0) { av[0] = (bf16)anc0; av[1] = (bf16)anc1; av[2] = (bf16)anc2; }
      bf16x8 bm = *(const bf16x8*)&MgR[512 + g * 8];
      sac = mfma16(av, bm, sac);
    }
    float dx = anc0 - ledp[a15 * 3 + 0];
    float dy = anc1 - ledp[a15 * 3 + 1];
    float dz = anc2 - ledp[a15 * 3 + 2];
    float cv = cvec[a15] - 0.5f * logf(dx * dx + dy * dy + dz * dz + 1e-8f);
#pragma unroll
    for (int rho = 0; rho < 4; ++rho) {
      int r = 4 * g + rho;
      int mrow = (r < 12) ? r : 11;
      float sc = sac[rho] + cv;
      if (fmask[mrow * 16 + a15] == 0) sc = -FLT_MAX;
      float mx = sc;
      mx = fmaxf(mx, __shfl_xor(mx, 1, 16));
      mx = fmaxf(mx, __shfl_xor(mx, 2, 16));
      mx = fmaxf(mx, __shfl_xor(mx, 4, 16));
      mx = fmaxf(mx, __shfl_xor(mx, 8, 16));
      float ev = expf(sc - mx);
      float sm = ev;
      sm += __shfl_xor(sm, 1, 16);
      sm += __shfl_xor(sm, 2, 16);
      sm += __shfl_xor(sm, 4, 16);
      sm += __shfl_xor(sm, 8, 16);
      if (r < 12) att[r * 16 + a15] = ev / sm;
    }
    // s_agg (96 items over 64 lanes)
    for (int it = lane; it < 96; it += 64) {
      int r = it >> 3, f = it & 7;
      float acc = 0.f;
#pragma unroll
      for (int n = 0; n < 16; ++n) acc += att[r * 16 + n] * ledf[n * 8 + f];
      sagg[it] = acc;
    }
    // s_feat
    {
      float acc = rb[lane];
      const f32x4* rwv = (const f32x4*)(rw + lane * 96);
#pragma unroll 6
      for (int i = 0; i < 24; ++i) {
        f32x4 a = rwv[i];
        f32x4 sv = *(const f32x4*)&sagg[i * 4];
        acc += a[0] * sv[0] + a[1] * sv[1] + a[2] * sv[2] + a[3] * sv[3];
      }
      comb[64 + lane] = fmaxf(acc, 0.f);
    }
  }
  __syncthreads();  // barrier B

  // ---- phase 2: conv2 (fp8 MFMA) + pooled mean ----
  {
    float tacc[4][4] = {{0.f, 0.f, 0.f, 0.f}, {0.f, 0.f, 0.f, 0.f},
                        {0.f, 0.f, 0.f, 0.f}, {0.f, 0.f, 0.f, 0.f}};
#pragma unroll
    for (int pti = 0; pti < 4; ++pti) {
      const int p = (wv * 4 + pti) * 16 + a15;
      f32x4 cc0 = {0.f, 0.f, 0.f, 0.f}, cc1 = {0.f, 0.f, 0.f, 0.f};
      f32x4 cc2 = {0.f, 0.f, 0.f, 0.f}, cc3 = {0.f, 0.f, 0.f, 0.f};
#pragma unroll
      for (int s = 0; s < 3; ++s) {
        i64 hv = *(const i64*)(h1b + (2 * p + s) * 40 + g * 8);
        cc0 = mfma8(w2f[0][s], hv, cc0);
        cc1 = mfma8(w2f[1][s], hv, cc1);
        cc2 = mfma8(w2f[2][s], hv, cc2);
        cc3 = mfma8(w2f[3][s], hv, cc3);
      }
#pragma unroll
      for (int r = 0; r < 4; ++r) {
        tacc[0][r] += fmaxf(cc0[r] + b2s[0][r], 0.f);
        tacc[1][r] += fmaxf(cc1[r] + b2s[1][r], 0.f);
        tacc[2][r] += fmaxf(cc2[r] + b2s[2][r], 0.f);
        tacc[3][r] += fmaxf(cc3[r] + b2s[3][r], 0.f);
      }
    }
#pragma unroll
    for (int o = 0; o < 4; ++o)
#pragma unroll
      for (int r = 0; r < 4; ++r) {
        float v = tacc[o][r];
        v += __shfl_xor(v, 1, 16);
        v += __shfl_xor(v, 2, 16);
        v += __shfl_xor(v, 4, 16);
        v += __shfl_xor(v, 8, 16);
        if (a15 == 0) tfp[wv * 64 + o * 16 + g * 4 + r] = v;
      }
  }
  __syncthreads();  // barrier C

  // ---- phase 3 (wave 0): t_feat finalize + fusion ----
  if (tid < 64) {
    comb[tid] = (tfp[tid] + tfp[64 + tid] + tfp[128 + tid] + tfp[192 + tid]) *
                (1.f / 4096.f);  // /256 mean * /16 weight scale
    float acc = fb[tid];
    const f32x4* fwv = (const f32x4*)(fw + tid * 128);
#pragma unroll 8
    for (int i = 0; i < 32; ++i) {
      f32x4 a = fwv[i];
      f32x4 c = *(const f32x4*)&comb[i * 4];
      acc += a[0] * c[0] + a[1] * c[1] + a[2] * c[2] + a[3] * c[3];
    }
    out[(size_t)b * 64 + tid] = acc;
  }
}

extern "C" void kernel_launch(void* const* d_in, const int* in_sizes, int n_in,
                              void* d_out, int out_size, void* d_ws, size_t ws_size,
                              hipStream_t stream) {
  (void)in_sizes; (void)n_in; (void)out_size; (void)ws_size;
  const float* rss   = (const float*)d_in[0];
  const float* anch  = (const float*)d_in[1];
  const float* ledf  = (const float*)d_in[2];
  const float* ledp  = (const float*)d_in[3];
  const int*   fmask = (const int*)d_in[4];
  const float* c1w = (const float*)d_in[5];
  const float* c1b = (const float*)d_in[6];
  const float* c2w = (const float*)d_in[7];
  const float* c2b = (const float*)d_in[8];
  const float* qw  = (const float*)d_in[9];
  const float* qb  = (const float*)d_in[10];
  const float* kw  = (const float*)d_in[11];
  const float* kb  = (const float*)d_in[12];
  const float* rw  = (const float*)d_in[13];
  const float* rb  = (const float*)d_in[14];
  const float* fw  = (const float*)d_in[15];
  const float* fb  = (const float*)d_in[16];
  float* outp = (float*)d_out;
  char* ws = (char*)d_ws;

  acek_pre<<<35, 256, 0, stream>>>(ledf, ledp, qw, qb, kw, kb, c1w, c2w, ws);
  acek_main<<<8192, 256, 0, stream>>>(
      rss, anch, ledf, ledp, fmask, c1b, c2b, rw, rb, fw, fb,
      (const bf16*)(ws + WS_MG), (const float*)(ws + WS_CVEC),
      (const bf16x8*)(ws + WS_W1F), (const i64*)(ws + WS_W2F), outp);
}